// Round 12
// baseline (88.569 us; speedup 1.0000x reference)
//
#include <hip/hip_runtime.h>
#include <hip/hip_bf16.h>

// Causal attention, B=2 H=16 S=2048 D=64, fp32 in/out.
// R12 = R11 + (a) V fragments direct from global (permuted V^T; 16B frags,
// L1-resident footprint, issued early) -- deletes V LDS reads+staging, the
// LDS pipe was ~25us of the 42.6; (b) QBLK=32 with 2-wave blocks -> grid
// 2048, 8 blocks/CU resident (2x independent chains, smoother tail).
// Swapped QK^T, in-register softmax (native exp2, defer-max local gate),
// MFMA l-sum (ones), peeled diagonal, permlane reduce, setprio,
// 2-phase double-buffered K staging via global_load_lds.

typedef __attribute__((ext_vector_type(8))) short bf16x8;
typedef __attribute__((ext_vector_type(4))) float f32x4;
typedef unsigned uint2v __attribute__((ext_vector_type(2)));

#define MFMA32K(a, b, c) __builtin_amdgcn_mfma_f32_16x16x32_bf16(a, b, c, 0, 0, 0)

constexpr int Bsz = 2, Hn = 16, Sn = 2048, Dn = 64;
constexpr int QBLK = 32, KBLK = 64;
constexpr int NE = Bsz * Hn * Sn * Dn;

#if defined(__has_builtin)
#if __has_builtin(__builtin_amdgcn_exp2f)
#define EXP2(x) __builtin_amdgcn_exp2f(x)
#endif
#endif
#ifndef EXP2
#define EXP2(x) exp2f(x)
#endif

__device__ inline short f2bf(float f) {
  union { float f; unsigned u; } v;
  v.f = f;
  unsigned r = v.u + 0x7FFF + ((v.u >> 16) & 1);  // RNE
  return (short)(r >> 16);
}

__device__ inline unsigned pk_bf16(float lo, float hi) {
  unsigned r;
  asm("v_cvt_pk_bf16_f32 %0, %1, %2" : "=v"(r) : "v"(lo), "v"(hi));
  return r;
}

__device__ inline void gl2lds16(const void* g, void* l) {
  __builtin_amdgcn_global_load_lds(
      (const __attribute__((address_space(1))) unsigned int*)g,
      (__attribute__((address_space(3))) unsigned int*)l, 16, 0, 0);
}

// K tile rows = 128B; XOR 16B-slot index with row&7 (involution, both sides)
__device__ inline int swz(int row, int colbyte) {
  return row * 128 + (colbyte ^ ((row & 7) << 4));
}

#if defined(__has_builtin)
#if __has_builtin(__builtin_amdgcn_permlane16_swap) && \
    __has_builtin(__builtin_amdgcn_permlane32_swap)
#define HAVE_PERMLANE_SWAP 1
#endif
#endif

__device__ inline float xred_max(float x) {
#ifdef HAVE_PERMLANE_SWAP
  uint2v a = __builtin_amdgcn_permlane16_swap(__float_as_uint(x),
                                              __float_as_uint(x), false, false);
  x = fmaxf(__uint_as_float(a[0]), __uint_as_float(a[1]));
  uint2v b = __builtin_amdgcn_permlane32_swap(__float_as_uint(x),
                                              __float_as_uint(x), false, false);
  x = fmaxf(__uint_as_float(b[0]), __uint_as_float(b[1]));
#else
  x = fmaxf(x, __shfl_xor(x, 16, 64));
  x = fmaxf(x, __shfl_xor(x, 32, 64));
#endif
  return x;
}

// ------- prepass (merged): z=0: K fp32->bf16; z=1: V -> V^T bf16 -------
// V^T columns permuted within each 64-tile: position p holds element
// k(p) = 32*(p>>5) + 16*((p>>2)&1) + 4*((p>>3)&3) + (p&3), so the PV
// A-fragment {k=32t2+4g+i} u {k=32t2+16+4g+i} is contiguous 16B at p=32t2+8g.
__global__ __launch_bounds__(256) void prep(const float* __restrict__ K,
                                            const float* __restrict__ V,
                                            short* __restrict__ Kb,
                                            short* __restrict__ Vt) {
  const int tile = blockIdx.x, bh = blockIdx.y;
  const int tid = threadIdx.x;
  const int r = tid >> 2, c = (tid & 3) * 16;
  const size_t base = (size_t)bh * Sn * Dn;

  if (blockIdx.z == 0) {
    const float* kp = K + base + (size_t)(tile * 64 + r) * Dn + c;
    float4 x0 = *(const float4*)(kp + 0);
    float4 x1 = *(const float4*)(kp + 4);
    float4 x2 = *(const float4*)(kp + 8);
    float4 x3 = *(const float4*)(kp + 12);
    bf16x8 w0, w1;
    w0[0] = f2bf(x0.x); w0[1] = f2bf(x0.y); w0[2] = f2bf(x0.z); w0[3] = f2bf(x0.w);
    w0[4] = f2bf(x1.x); w0[5] = f2bf(x1.y); w0[6] = f2bf(x1.z); w0[7] = f2bf(x1.w);
    w1[0] = f2bf(x2.x); w1[1] = f2bf(x2.y); w1[2] = f2bf(x2.z); w1[3] = f2bf(x2.w);
    w1[4] = f2bf(x3.x); w1[5] = f2bf(x3.y); w1[6] = f2bf(x3.z); w1[7] = f2bf(x3.w);
    short* op = Kb + base + (size_t)(tile * 64 + r) * Dn + c;
    *(bf16x8*)op = w0;
    *(bf16x8*)(op + 8) = w1;
  } else {
    __shared__ short t[64][66];  // +2 pad
    const float* vp = V + base + (size_t)(tile * 64 + r) * Dn + c;
    float4 x0 = *(const float4*)(vp + 0);
    float4 x1 = *(const float4*)(vp + 4);
    float4 x2 = *(const float4*)(vp + 8);
    float4 x3 = *(const float4*)(vp + 12);
    short* tr = &t[r][c];
    tr[0] = f2bf(x0.x); tr[1] = f2bf(x0.y); tr[2] = f2bf(x0.z); tr[3] = f2bf(x0.w);
    tr[4] = f2bf(x1.x); tr[5] = f2bf(x1.y); tr[6] = f2bf(x1.z); tr[7] = f2bf(x1.w);
    tr[8] = f2bf(x2.x); tr[9] = f2bf(x2.y); tr[10] = f2bf(x2.z); tr[11] = f2bf(x2.w);
    tr[12] = f2bf(x3.x); tr[13] = f2bf(x3.y); tr[14] = f2bf(x3.z); tr[15] = f2bf(x3.w);
    __syncthreads();
    short* op = Vt + base + (size_t)r * Sn + tile * 64 + c;
    bf16x8 w0, w1;
#pragma unroll
    for (int j = 0; j < 8; ++j) {
      int p0 = c + j, p1 = c + 8 + j;
      int k0 = 32 * (p0 >> 5) + 16 * ((p0 >> 2) & 1) + 4 * ((p0 >> 3) & 3) + (p0 & 3);
      int k1 = 32 * (p1 >> 5) + 16 * ((p1 >> 2) & 1) + 4 * ((p1 >> 3) & 3) + (p1 & 3);
      w0[j] = t[k0][r];
      w1[j] = t[k1][r];
    }
    *(bf16x8*)op = w0;
    *(bf16x8*)(op + 8) = w1;
  }
}

// ---------------------------- main attention ----------------------------
// 128-thread blocks (2 waves x 16 q-rows = QBLK 32); grid (32 bh, 64 qt).
__global__ __launch_bounds__(128) void attn_fwd(
    const float* __restrict__ Q, const short* __restrict__ Kb,
    const short* __restrict__ Vt, const float* __restrict__ SF,
    float* __restrict__ O) {
  __shared__ short Kbuf[2][64 * 64];   // [k][d] bf16, swizzled (16 KB)

  const int bh = blockIdx.x;
  const int qtq = (gridDim.y - 1) - blockIdx.y;  // q-tile (32 rows), heavy-first
  const int tid = threadIdx.x;
  const int wave = tid >> 6, lane = tid & 63;
  const int g = lane >> 4, lc = lane & 15;
  const float qscale = 1.4426950408889634f / SF[0];  // exp2 domain

  const size_t base = (size_t)bh * Sn * Dn;
  const int qg = qtq * QBLK + wave * 16 + lc;  // this lane's q row
  const int nkv = (qtq >> 1) + 1;              // KV tiles (64 wide) to visit

  // hoisted per-lane K fragment LDS offsets (loop-invariant)
  int ka[4][2];
#pragma unroll
  for (int t = 0; t < 4; ++t) {
    ka[t][0] = swz(t * 16 + lc, g * 16);
    ka[t][1] = swz(t * 16 + lc, g * 16 + 64);
  }
  // hoisted K staging source offsets (2 waves x 4 chunks of 1KB = 8KB tile)
  int koff[4];
#pragma unroll
  for (int j = 0; j < 4; ++j) {
    int off = (wave * 4 + j) * 1024 + lane * 16;
    int row = off >> 7;
    koff[j] = row * 128 + ((off & 127) ^ ((row & 7) << 4));
  }

  const char* kpg = (const char*)(Kb + base);
  auto stageK = [&](int buf) {
#pragma unroll
    for (int j = 0; j < 4; ++j)
      gl2lds16(kpg + koff[j], (char*)Kbuf[buf] + (wave * 4 + j) * 1024);
    kpg += KBLK * Dn * 2;
  };

  // V^T per-lane global row bases (permuted layout; 16B frag per (t2,dt))
  const char* vb[4];
#pragma unroll
  for (int dt = 0; dt < 4; ++dt)
    vb[dt] = (const char*)(Vt + base) + (size_t)(dt * 16 + lc) * (Sn * 2) + g * 16;

  // ---- Q fragment (B operand): elem j = Q[qg][g*8+32h+j] * qscale ----
  bf16x8 bq[2];
  {
    const float* qp = Q + base + (size_t)qg * Dn + g * 8;
#pragma unroll
    for (int h = 0; h < 2; ++h) {
      float4 x0 = *(const float4*)(qp + 32 * h);
      float4 x1 = *(const float4*)(qp + 32 * h + 4);
      bf16x8 a;
      a[0] = f2bf(x0.x * qscale); a[1] = f2bf(x0.y * qscale);
      a[2] = f2bf(x0.z * qscale); a[3] = f2bf(x0.w * qscale);
      a[4] = f2bf(x1.x * qscale); a[5] = f2bf(x1.y * qscale);
      a[6] = f2bf(x1.z * qscale); a[7] = f2bf(x1.w * qscale);
      bq[h] = a;
    }
  }

  // all-ones A-fragment for the l-accumulating MFMA (bf16 1.0 = 0x3F80)
  bf16x8 ones;
#pragma unroll
  for (int j = 0; j < 8; ++j) ones[j] = (short)0x3F80;

  f32x4 o[4], lsum = (f32x4){0.f, 0.f, 0.f, 0.f};
#pragma unroll
  for (int dt = 0; dt < 4; ++dt) o[dt] = (f32x4){0.f, 0.f, 0.f, 0.f};
  float m = -10000.0f;  // finite sentinel; first tile always rescales

  int cur = 0;
  stageK(0);
  __syncthreads();

  // per-tile body; masked=true only for the peeled diagonal tile
  auto tile_body = [&](int cur_, int kt, bool do_stage, bool masked, int kb) {
    // ---- V fragments: direct global -> regs (issued early, used late) ----
    bf16x8 vf[2][4];
#pragma unroll
    for (int t2 = 0; t2 < 2; ++t2)
#pragma unroll
      for (int dt = 0; dt < 4; ++dt)
        vf[t2][dt] = *(const bf16x8*)(vb[dt] + kt * 128 + t2 * 64);

    if (do_stage) stageK(cur_ ^ 1);

    const char* Kc = (const char*)Kbuf[cur_];

    // ---- swapped QK^T: s[t][i] = S[q=qg][k = kb+t*16+g*4+i] ----
    f32x4 s[4];
    __builtin_amdgcn_s_setprio(1);
#pragma unroll
    for (int t = 0; t < 4; ++t) {
      bf16x8 ak0 = *(const bf16x8*)(Kc + ka[t][0]);
      bf16x8 ak1 = *(const bf16x8*)(Kc + ka[t][1]);
      f32x4 z = (f32x4){0.f, 0.f, 0.f, 0.f};
      z = MFMA32K(ak0, bq[0], z);
      z = MFMA32K(ak1, bq[1], z);
      s[t] = z;
    }
    __builtin_amdgcn_s_setprio(0);

    if (masked) {
#pragma unroll
      for (int t = 0; t < 4; ++t)
#pragma unroll
        for (int i = 0; i < 4; ++i) {
          int kg = kb + t * 16 + g * 4 + i;
          if (kg > qg) s[t][i] = -30000.0f;
        }
    }

    // ---- softmax (exp2 domain), defer-max THR=8, local gate ----
    float a0 = fmaxf(fmaxf(s[0][0], s[0][1]), s[0][2]);
    float a1 = fmaxf(fmaxf(s[0][3], s[1][0]), s[1][1]);
    float a2 = fmaxf(fmaxf(s[1][2], s[1][3]), s[2][0]);
    float a3 = fmaxf(fmaxf(s[2][1], s[2][2]), s[2][3]);
    float a4 = fmaxf(fmaxf(s[3][0], s[3][1]), s[3][2]);
    float b0 = fmaxf(fmaxf(a0, a1), a2);
    float b1 = fmaxf(fmaxf(a3, a4), s[3][3]);
    float plocal = fmaxf(b0, b1);
    if (!__all(plocal - m <= 8.0f)) {
      float pmax = xred_max(plocal);     // row max (only when rescaling)
      float mnew = fmaxf(m, pmax);
      float alpha = EXP2(m - mnew);
      lsum[0] *= alpha;  // only [0] is ever read
#pragma unroll
      for (int dt = 0; dt < 4; ++dt) o[dt] *= alpha;
      m = mnew;
    }
#pragma unroll
    for (int t = 0; t < 4; ++t)
#pragma unroll
      for (int i = 0; i < 4; ++i) s[t][i] = EXP2(s[t][i] - m);

    // ---- pack P; PV + l via MFMA (ones-column), reg-resident V ----
    union { unsigned uu[4]; bf16x8 v; } pb[2];
#pragma unroll
    for (int t2 = 0; t2 < 2; ++t2) {
      pb[t2].uu[0] = pk_bf16(s[2 * t2][0], s[2 * t2][1]);
      pb[t2].uu[1] = pk_bf16(s[2 * t2][2], s[2 * t2][3]);
      pb[t2].uu[2] = pk_bf16(s[2 * t2 + 1][0], s[2 * t2 + 1][1]);
      pb[t2].uu[3] = pk_bf16(s[2 * t2 + 1][2], s[2 * t2 + 1][3]);
    }
    __builtin_amdgcn_s_setprio(1);
#pragma unroll
    for (int t2 = 0; t2 < 2; ++t2) {
      lsum = MFMA32K(ones, pb[t2].v, lsum);
#pragma unroll
      for (int dt = 0; dt < 4; ++dt)
        o[dt] = MFMA32K(vf[t2][dt], pb[t2].v, o[dt]);
    }
    __builtin_amdgcn_s_setprio(0);

    if (do_stage) __syncthreads();  // next K landed + cur fully consumed
  };

  // ---- main loop: KV tiles 0..nkv-2, branch/mask-free ----
  for (int kt = 0; kt < nkv - 1; ++kt) {
    tile_body(cur, kt, true, false, 0);
    cur ^= 1;
  }
  // ---- peeled diagonal KV tile ----
  tile_body(cur, nkv - 1, false, true, (nkv - 1) * KBLK);

  // ---- epilogue: O[q][d] = o / l, coalesced f32x4 stores ----
  const float inv = 1.0f / lsum[0];
  float* op = O + base + (size_t)qg * Dn;
#pragma unroll
  for (int dt = 0; dt < 4; ++dt) {
    f32x4 r = o[dt] * inv;
    *(f32x4*)(op + dt * 16 + g * 4) = r;
  }
}

extern "C" void kernel_launch(void* const* d_in, const int* in_sizes, int n_in,
                              void* d_out, int out_size, void* d_ws, size_t ws_size,
                              hipStream_t stream) {
  const float* Q = (const float*)d_in[0];
  const float* K = (const float*)d_in[1];
  const float* V = (const float*)d_in[2];
  const float* SF = (const float*)d_in[3];
  // d_in[4] causal mask: tril by construction -> applied analytically (k<=q).
  float* O = (float*)d_out;

  short* Kb = (short*)d_ws;  // [B*H][2048][64] bf16
  short* Vt = Kb + NE;       // [B*H][64][2048] bf16 (column-permuted per tile)

  prep<<<dim3(Sn / 64, Bsz * Hn, 2), 256, 0, stream>>>(K, V, Kb, Vt);
  attn_fwd<<<dim3(Bsz * Hn, Sn / QBLK), 128, 0, stream>>>(Q, Kb, Vt, SF, O);
}

// Round 14
// 51.167 us; speedup vs baseline: 1.7310x; 1.7310x over previous
//
#include <hip/hip_runtime.h>
#include <hip/hip_bf16.h>

// Causal attention, B=2 H=16 S=2048 D=64, fp32 in/out.
// R14 = R11 (best verified: 42.6us main) + (1) setprio removed (m190:
// negative on barrier-locked multi-wave structures) + (2) prep fused to one
// 1024-block launch (K convert + V transpose per block).
// Swapped QK^T, in-register softmax (native exp2, defer-max local gate),
// MFMA l-sum (ones column), permuted-V^T zero-conflict b128 PV, permlane
// reduce, peeled diagonal tile, 2-phase double-buffered global_load_lds
// staging, heavy-first dispatch.

typedef __attribute__((ext_vector_type(8))) short bf16x8;
typedef __attribute__((ext_vector_type(4))) float f32x4;
typedef unsigned uint2v __attribute__((ext_vector_type(2)));

#define MFMA32K(a, b, c) __builtin_amdgcn_mfma_f32_16x16x32_bf16(a, b, c, 0, 0, 0)

constexpr int Bsz = 2, Hn = 16, Sn = 2048, Dn = 64;
constexpr int QBLK = 64, KBLK = 64;
constexpr int NE = Bsz * Hn * Sn * Dn;

#if defined(__has_builtin)
#if __has_builtin(__builtin_amdgcn_exp2f)
#define EXP2(x) __builtin_amdgcn_exp2f(x)
#endif
#endif
#ifndef EXP2
#define EXP2(x) exp2f(x)
#endif

__device__ inline short f2bf(float f) {
  union { float f; unsigned u; } v;
  v.f = f;
  unsigned r = v.u + 0x7FFF + ((v.u >> 16) & 1);  // RNE
  return (short)(r >> 16);
}

__device__ inline unsigned pk_bf16(float lo, float hi) {
  unsigned r;
  asm("v_cvt_pk_bf16_f32 %0, %1, %2" : "=v"(r) : "v"(lo), "v"(hi));
  return r;
}

__device__ inline void gl2lds16(const void* g, void* l) {
  __builtin_amdgcn_global_load_lds(
      (const __attribute__((address_space(1))) unsigned int*)g,
      (__attribute__((address_space(3))) unsigned int*)l, 16, 0, 0);
}

// tile rows = 128B; XOR 16B-slot index with row&7 (involution, both sides)
__device__ inline int swz(int row, int colbyte) {
  return row * 128 + (colbyte ^ ((row & 7) << 4));
}

#if defined(__has_builtin)
#if __has_builtin(__builtin_amdgcn_permlane16_swap) && \
    __has_builtin(__builtin_amdgcn_permlane32_swap)
#define HAVE_PERMLANE_SWAP 1
#endif
#endif

__device__ inline float xred_max(float x) {
#ifdef HAVE_PERMLANE_SWAP
  uint2v a = __builtin_amdgcn_permlane16_swap(__float_as_uint(x),
                                              __float_as_uint(x), false, false);
  x = fmaxf(__uint_as_float(a[0]), __uint_as_float(a[1]));
  uint2v b = __builtin_amdgcn_permlane32_swap(__float_as_uint(x),
                                              __float_as_uint(x), false, false);
  x = fmaxf(__uint_as_float(b[0]), __uint_as_float(b[1]));
#else
  x = fmaxf(x, __shfl_xor(x, 16, 64));
  x = fmaxf(x, __shfl_xor(x, 32, 64));
#endif
  return x;
}

// ---------- fused prepass: K fp32->bf16 AND V -> V^T bf16 per tile ----------
// V^T columns permuted within each 64-tile: position p holds element
// k(p) = 32*(p>>5) + 16*((p>>2)&1) + 4*((p>>3)&3) + (p&3), so the PV
// A-fragment {k=32t2+4g+i} u {k=32t2+16+4g+i} is contiguous 16B at p=32t2+8g.
__global__ __launch_bounds__(256) void prep(const float* __restrict__ K,
                                            const float* __restrict__ V,
                                            short* __restrict__ Kb,
                                            short* __restrict__ Vt) {
  __shared__ short t[64][66];  // +2 pad
  const int tile = blockIdx.x, bh = blockIdx.y;
  const int tid = threadIdx.x;
  const int r = tid >> 2, c = (tid & 3) * 16;
  const size_t base = (size_t)bh * Sn * Dn;

  // ---- K: elementwise fp32 -> bf16 ----
  {
    const float* kp = K + base + (size_t)(tile * 64 + r) * Dn + c;
    float4 x0 = *(const float4*)(kp + 0);
    float4 x1 = *(const float4*)(kp + 4);
    float4 x2 = *(const float4*)(kp + 8);
    float4 x3 = *(const float4*)(kp + 12);
    bf16x8 w0, w1;
    w0[0] = f2bf(x0.x); w0[1] = f2bf(x0.y); w0[2] = f2bf(x0.z); w0[3] = f2bf(x0.w);
    w0[4] = f2bf(x1.x); w0[5] = f2bf(x1.y); w0[6] = f2bf(x1.z); w0[7] = f2bf(x1.w);
    w1[0] = f2bf(x2.x); w1[1] = f2bf(x2.y); w1[2] = f2bf(x2.z); w1[3] = f2bf(x2.w);
    w1[4] = f2bf(x3.x); w1[5] = f2bf(x3.y); w1[6] = f2bf(x3.z); w1[7] = f2bf(x3.w);
    short* op = Kb + base + (size_t)(tile * 64 + r) * Dn + c;
    *(bf16x8*)op = w0;
    *(bf16x8*)(op + 8) = w1;
  }

  // ---- V: transpose tile -> Vt[bh][d][k] bf16 (column-permuted) ----
  {
    const float* vp = V + base + (size_t)(tile * 64 + r) * Dn + c;
    float4 x0 = *(const float4*)(vp + 0);
    float4 x1 = *(const float4*)(vp + 4);
    float4 x2 = *(const float4*)(vp + 8);
    float4 x3 = *(const float4*)(vp + 12);
    short* tr = &t[r][c];
    tr[0] = f2bf(x0.x); tr[1] = f2bf(x0.y); tr[2] = f2bf(x0.z); tr[3] = f2bf(x0.w);
    tr[4] = f2bf(x1.x); tr[5] = f2bf(x1.y); tr[6] = f2bf(x1.z); tr[7] = f2bf(x1.w);
    tr[8] = f2bf(x2.x); tr[9] = f2bf(x2.y); tr[10] = f2bf(x2.z); tr[11] = f2bf(x2.w);
    tr[12] = f2bf(x3.x); tr[13] = f2bf(x3.y); tr[14] = f2bf(x3.z); tr[15] = f2bf(x3.w);
    __syncthreads();
    short* op = Vt + base + (size_t)r * Sn + tile * 64 + c;
    bf16x8 w0, w1;
#pragma unroll
    for (int j = 0; j < 8; ++j) {
      int p0 = c + j, p1 = c + 8 + j;
      int k0 = 32 * (p0 >> 5) + 16 * ((p0 >> 2) & 1) + 4 * ((p0 >> 3) & 3) + (p0 & 3);
      int k1 = 32 * (p1 >> 5) + 16 * ((p1 >> 2) & 1) + 4 * ((p1 >> 3) & 3) + (p1 & 3);
      w0[j] = t[k0][r];
      w1[j] = t[k1][r];
    }
    *(bf16x8*)op = w0;
    *(bf16x8*)(op + 8) = w1;
  }
}

// ---------------------------- main attention ----------------------------
__global__ __launch_bounds__(256, 4) void attn_fwd(
    const float* __restrict__ Q, const short* __restrict__ Kb,
    const short* __restrict__ Vt, const float* __restrict__ SF,
    float* __restrict__ O) {
  __shared__ short Kbuf[2][64 * 64];   // [k][d] bf16, swizzled
  __shared__ short Vbuf[2][64 * 64];   // [d][p(k)] bf16, swizzled

  const int bh = blockIdx.x;
  const int qt = (gridDim.y - 1) - blockIdx.y;  // heavy-first
  const int tid = threadIdx.x;
  const int wave = tid >> 6, lane = tid & 63;
  const int g = lane >> 4, lc = lane & 15;
  const float qscale = 1.4426950408889634f / SF[0];  // exp2 domain

  const size_t base = (size_t)bh * Sn * Dn;
  const int qg = qt * QBLK + wave * 16 + lc;  // this lane's q row

  // hoisted per-lane fragment LDS offsets (loop-invariant)
  int ka[4][2], va[2][4];
#pragma unroll
  for (int t = 0; t < 4; ++t) {
    ka[t][0] = swz(t * 16 + lc, g * 16);
    ka[t][1] = swz(t * 16 + lc, g * 16 + 64);
  }
#pragma unroll
  for (int t2 = 0; t2 < 2; ++t2)
#pragma unroll
    for (int dt = 0; dt < 4; ++dt)
      va[t2][dt] = swz(dt * 16 + lc, t2 * 64 + g * 16);
  // hoisted staging source offsets (within a tile)
  int koff[2], voff[2];
#pragma unroll
  for (int j = 0; j < 2; ++j) {
    int c = wave * 2 + j;
    int off = c * 1024 + lane * 16;
    int row = off >> 7;
    int col = (off & 127) ^ ((row & 7) << 4);
    koff[j] = row * 128 + col;
    voff[j] = row * (Sn * 2) + col;
  }

  const char* kpg = (const char*)(Kb + base);
  const char* vpg = (const char*)(Vt + base);

  auto stageK = [&](int buf) {
#pragma unroll
    for (int j = 0; j < 2; ++j)
      gl2lds16(kpg + koff[j], (char*)Kbuf[buf] + (wave * 2 + j) * 1024);
    kpg += KBLK * Dn * 2;
  };
  auto stageV = [&](int buf) {
#pragma unroll
    for (int j = 0; j < 2; ++j)
      gl2lds16(vpg + voff[j], (char*)Vbuf[buf] + (wave * 2 + j) * 1024);
    vpg += KBLK * 2;
  };

  // ---- Q fragment (B operand): elem j = Q[qg][g*8+32h+j] * qscale ----
  bf16x8 bq[2];
  {
    const float* qp = Q + base + (size_t)qg * Dn + g * 8;
#pragma unroll
    for (int h = 0; h < 2; ++h) {
      float4 x0 = *(const float4*)(qp + 32 * h);
      float4 x1 = *(const float4*)(qp + 32 * h + 4);
      bf16x8 a;
      a[0] = f2bf(x0.x * qscale); a[1] = f2bf(x0.y * qscale);
      a[2] = f2bf(x0.z * qscale); a[3] = f2bf(x0.w * qscale);
      a[4] = f2bf(x1.x * qscale); a[5] = f2bf(x1.y * qscale);
      a[6] = f2bf(x1.z * qscale); a[7] = f2bf(x1.w * qscale);
      bq[h] = a;
    }
  }

  // all-ones A-fragment for the l-accumulating MFMA (bf16 1.0 = 0x3F80)
  bf16x8 ones;
#pragma unroll
  for (int j = 0; j < 8; ++j) ones[j] = (short)0x3F80;

  f32x4 o[4], lsum = (f32x4){0.f, 0.f, 0.f, 0.f};
#pragma unroll
  for (int dt = 0; dt < 4; ++dt) o[dt] = (f32x4){0.f, 0.f, 0.f, 0.f};
  float m = -10000.0f;  // finite sentinel; first tile always rescales

  int cur = 0;
  stageK(0);
  stageV(0);
  __syncthreads();

  // shared per-tile body; masked=true only for the peeled diagonal tile
  auto tile_body = [&](int cur_, bool masked, int kb) {
    const char* Kc = (const char*)Kbuf[cur_];
    const char* Vc = (const char*)Vbuf[cur_];

    // ---- swapped QK^T: s[t][i] = S[q=qg][k = kb+t*16+g*4+i] ----
    f32x4 s[4];
#pragma unroll
    for (int t = 0; t < 4; ++t) {
      bf16x8 ak0 = *(const bf16x8*)(Kc + ka[t][0]);
      bf16x8 ak1 = *(const bf16x8*)(Kc + ka[t][1]);
      f32x4 z = (f32x4){0.f, 0.f, 0.f, 0.f};
      z = MFMA32K(ak0, bq[0], z);
      z = MFMA32K(ak1, bq[1], z);
      s[t] = z;
    }

    if (masked) {
#pragma unroll
      for (int t = 0; t < 4; ++t)
#pragma unroll
        for (int i = 0; i < 4; ++i) {
          int kg = kb + t * 16 + g * 4 + i;
          if (kg > qg) s[t][i] = -30000.0f;
        }
    }

    // ---- softmax (exp2 domain), defer-max THR=8 with LOCAL gate ----
    float a0 = fmaxf(fmaxf(s[0][0], s[0][1]), s[0][2]);
    float a1 = fmaxf(fmaxf(s[0][3], s[1][0]), s[1][1]);
    float a2 = fmaxf(fmaxf(s[1][2], s[1][3]), s[2][0]);
    float a3 = fmaxf(fmaxf(s[2][1], s[2][2]), s[2][3]);
    float a4 = fmaxf(fmaxf(s[3][0], s[3][1]), s[3][2]);
    float b0 = fmaxf(fmaxf(a0, a1), a2);
    float b1 = fmaxf(fmaxf(a3, a4), s[3][3]);
    float plocal = fmaxf(b0, b1);
    if (!__all(plocal - m <= 8.0f)) {
      float pmax = xred_max(plocal);     // row max (only when rescaling)
      float mnew = fmaxf(m, pmax);
      float alpha = EXP2(m - mnew);
      lsum[0] *= alpha;  // only [0] is ever read
#pragma unroll
      for (int dt = 0; dt < 4; ++dt) o[dt] *= alpha;
      m = mnew;
    }
#pragma unroll
    for (int t = 0; t < 4; ++t)
#pragma unroll
      for (int i = 0; i < 4; ++i) s[t][i] = EXP2(s[t][i] - m);

    // ---- pack P; PV + l via MFMA (ones-column), zero-conflict b128 ----
    union { unsigned uu[4]; bf16x8 v; } pb[2];
#pragma unroll
    for (int t2 = 0; t2 < 2; ++t2) {
      pb[t2].uu[0] = pk_bf16(s[2 * t2][0], s[2 * t2][1]);
      pb[t2].uu[1] = pk_bf16(s[2 * t2][2], s[2 * t2][3]);
      pb[t2].uu[2] = pk_bf16(s[2 * t2 + 1][0], s[2 * t2 + 1][1]);
      pb[t2].uu[3] = pk_bf16(s[2 * t2 + 1][2], s[2 * t2 + 1][3]);
    }
#pragma unroll
    for (int t2 = 0; t2 < 2; ++t2) {
      lsum = MFMA32K(ones, pb[t2].v, lsum);
#pragma unroll
      for (int dt = 0; dt < 4; ++dt) {
        bf16x8 av = *(const bf16x8*)(Vc + va[t2][dt]);
        o[dt] = MFMA32K(av, pb[t2].v, o[dt]);
      }
    }

    __syncthreads();  // next tile landed (vmcnt) + cur fully consumed
  };

  // ---- main loop: kt = 0..qt-1, branch/mask-free ----
  for (int kt = 0; kt < qt; ++kt) {
    stageK(cur ^ 1);             // stage tile kt+1 (kt+1 <= qt always here)
    stageV(cur ^ 1);
    tile_body(cur, false, 0);
    cur ^= 1;
  }
  // ---- peeled diagonal tile (kt == qt): mask active, no next stage ----
  tile_body(cur, true, qt * KBLK);

  // ---- epilogue: O[q][d] = o / l, coalesced f32x4 stores ----
  const float inv = 1.0f / lsum[0];
  float* op = O + base + (size_t)qg * Dn;
#pragma unroll
  for (int dt = 0; dt < 4; ++dt) {
    f32x4 r = o[dt] * inv;
    *(f32x4*)(op + dt * 16 + g * 4) = r;
  }
}

extern "C" void kernel_launch(void* const* d_in, const int* in_sizes, int n_in,
                              void* d_out, int out_size, void* d_ws, size_t ws_size,
                              hipStream_t stream) {
  const float* Q = (const float*)d_in[0];
  const float* K = (const float*)d_in[1];
  const float* V = (const float*)d_in[2];
  const float* SF = (const float*)d_in[3];
  // d_in[4] causal mask: tril by construction -> applied analytically (k<=q).
  float* O = (float*)d_out;

  short* Kb = (short*)d_ws;  // [B*H][2048][64] bf16
  short* Vt = Kb + NE;       // [B*H][64][2048] bf16 (column-permuted per tile)

  prep<<<dim3(Sn / 64, Bsz * Hn), 256, 0, stream>>>(K, V, Kb, Vt);
  attn_fwd<<<dim3(Bsz * Hn, Sn / QBLK), 256, 0, stream>>>(Q, Kb, Vt, SF, O);
}

// Round 15
// 44.393 us; speedup vs baseline: 1.9951x; 1.1526x over previous
//
#include <hip/hip_runtime.h>
#include <hip/hip_bf16.h>

// Causal attention, B=2 H=16 S=2048 D=64, fp32 in/out.
// R15: q-half x KV-parity wave split on the verified 16x16 structure.
// Each wave: 32 q-rows (2 fragments), KV tiles of its parity only; K/V LDS
// fragments read ONCE per tile, reused for both q-fragments -> block LDS
// reads per tile-visit halved (64 -> 32 b128). Grid stays 1024. Private
// (m,l,o) per wave, merged once per block via LDS. setprio restored (R14
// A/B: removal cost 3us). Swapped QK^T, in-register softmax (native exp2,
// defer-max local gate), MFMA l-sum (ones), permuted-V^T zero-conflict b128
// PV, permlane reduce, pair-wise global_load_lds staging, heavy-first.

typedef __attribute__((ext_vector_type(8))) short bf16x8;
typedef __attribute__((ext_vector_type(4))) float f32x4;
typedef unsigned uint2v __attribute__((ext_vector_type(2)));

#define MFMA32K(a, b, c) __builtin_amdgcn_mfma_f32_16x16x32_bf16(a, b, c, 0, 0, 0)

constexpr int Bsz = 2, Hn = 16, Sn = 2048, Dn = 64;
constexpr int KBLK = 64;
constexpr int NE = Bsz * Hn * Sn * Dn;

#if defined(__has_builtin)
#if __has_builtin(__builtin_amdgcn_exp2f)
#define EXP2(x) __builtin_amdgcn_exp2f(x)
#endif
#endif
#ifndef EXP2
#define EXP2(x) exp2f(x)
#endif

__device__ inline short f2bf(float f) {
  union { float f; unsigned u; } v;
  v.f = f;
  unsigned r = v.u + 0x7FFF + ((v.u >> 16) & 1);  // RNE
  return (short)(r >> 16);
}

__device__ inline unsigned pk_bf16(float lo, float hi) {
  unsigned r;
  asm("v_cvt_pk_bf16_f32 %0, %1, %2" : "=v"(r) : "v"(lo), "v"(hi));
  return r;
}

__device__ inline void gl2lds16(const void* g, void* l) {
  __builtin_amdgcn_global_load_lds(
      (const __attribute__((address_space(1))) unsigned int*)g,
      (__attribute__((address_space(3))) unsigned int*)l, 16, 0, 0);
}

// tile rows = 128B; XOR 16B-slot index with row&7 (involution, both sides)
__device__ inline int swz(int row, int colbyte) {
  return row * 128 + (colbyte ^ ((row & 7) << 4));
}

#if defined(__has_builtin)
#if __has_builtin(__builtin_amdgcn_permlane16_swap) && \
    __has_builtin(__builtin_amdgcn_permlane32_swap)
#define HAVE_PERMLANE_SWAP 1
#endif
#endif

__device__ inline float xred_max(float x) {
#ifdef HAVE_PERMLANE_SWAP
  uint2v a = __builtin_amdgcn_permlane16_swap(__float_as_uint(x),
                                              __float_as_uint(x), false, false);
  x = fmaxf(__uint_as_float(a[0]), __uint_as_float(a[1]));
  uint2v b = __builtin_amdgcn_permlane32_swap(__float_as_uint(x),
                                              __float_as_uint(x), false, false);
  x = fmaxf(__uint_as_float(b[0]), __uint_as_float(b[1]));
#else
  x = fmaxf(x, __shfl_xor(x, 16, 64));
  x = fmaxf(x, __shfl_xor(x, 32, 64));
#endif
  return x;
}

// ---------- fused prepass: K fp32->bf16 AND V -> V^T bf16 per tile ----------
// V^T columns permuted within each 64-tile (R11 16x16 map): position p holds
// k(p) = 32*(p>>5) + 16*((p>>2)&1) + 4*((p>>3)&3) + (p&3).
__global__ __launch_bounds__(256) void prep(const float* __restrict__ K,
                                            const float* __restrict__ V,
                                            short* __restrict__ Kb,
                                            short* __restrict__ Vt) {
  __shared__ short t[64][66];  // +2 pad
  const int tile = blockIdx.x, bh = blockIdx.y;
  const int tid = threadIdx.x;
  const int r = tid >> 2, c = (tid & 3) * 16;
  const size_t base = (size_t)bh * Sn * Dn;

  {
    const float* kp = K + base + (size_t)(tile * 64 + r) * Dn + c;
    float4 x0 = *(const float4*)(kp + 0);
    float4 x1 = *(const float4*)(kp + 4);
    float4 x2 = *(const float4*)(kp + 8);
    float4 x3 = *(const float4*)(kp + 12);
    bf16x8 w0, w1;
    w0[0] = f2bf(x0.x); w0[1] = f2bf(x0.y); w0[2] = f2bf(x0.z); w0[3] = f2bf(x0.w);
    w0[4] = f2bf(x1.x); w0[5] = f2bf(x1.y); w0[6] = f2bf(x1.z); w0[7] = f2bf(x1.w);
    w1[0] = f2bf(x2.x); w1[1] = f2bf(x2.y); w1[2] = f2bf(x2.z); w1[3] = f2bf(x2.w);
    w1[4] = f2bf(x3.x); w1[5] = f2bf(x3.y); w1[6] = f2bf(x3.z); w1[7] = f2bf(x3.w);
    short* op = Kb + base + (size_t)(tile * 64 + r) * Dn + c;
    *(bf16x8*)op = w0;
    *(bf16x8*)(op + 8) = w1;
  }
  {
    const float* vp = V + base + (size_t)(tile * 64 + r) * Dn + c;
    float4 x0 = *(const float4*)(vp + 0);
    float4 x1 = *(const float4*)(vp + 4);
    float4 x2 = *(const float4*)(vp + 8);
    float4 x3 = *(const float4*)(vp + 12);
    short* tr = &t[r][c];
    tr[0] = f2bf(x0.x); tr[1] = f2bf(x0.y); tr[2] = f2bf(x0.z); tr[3] = f2bf(x0.w);
    tr[4] = f2bf(x1.x); tr[5] = f2bf(x1.y); tr[6] = f2bf(x1.z); tr[7] = f2bf(x1.w);
    tr[8] = f2bf(x2.x); tr[9] = f2bf(x2.y); tr[10] = f2bf(x2.z); tr[11] = f2bf(x2.w);
    tr[12] = f2bf(x3.x); tr[13] = f2bf(x3.y); tr[14] = f2bf(x3.z); tr[15] = f2bf(x3.w);
    __syncthreads();
    short* op = Vt + base + (size_t)r * Sn + tile * 64 + c;
    bf16x8 w0, w1;
#pragma unroll
    for (int j = 0; j < 8; ++j) {
      int p0 = c + j, p1 = c + 8 + j;
      int k0 = 32 * (p0 >> 5) + 16 * ((p0 >> 2) & 1) + 4 * ((p0 >> 3) & 3) + (p0 & 3);
      int k1 = 32 * (p1 >> 5) + 16 * ((p1 >> 2) & 1) + 4 * ((p1 >> 3) & 3) + (p1 & 3);
      w0[j] = t[k0][r];
      w1[j] = t[k1][r];
    }
    *(bf16x8*)op = w0;
    *(bf16x8*)(op + 8) = w1;
  }
}

// ---------------------------- main attention ----------------------------
// 4 waves = (qh, par): wave = 2*qh + par. Wave owns q rows
// qt*64 + qh*32 + u*16 + lc (u=0,1) over KV tiles with kt&1 == par.
__global__ __launch_bounds__(256, 4) void attn_fwd(
    const float* __restrict__ Q, const short* __restrict__ Kb,
    const short* __restrict__ Vt, const float* __restrict__ SF,
    float* __restrict__ O) {
  __shared__ short Kbuf[2][64 * 64];   // buffer index = tile parity
  __shared__ short Vbuf[2][64 * 64];

  const int bh = blockIdx.x;
  const int qt = (gridDim.y - 1) - blockIdx.y;  // heavy-first, [0,32)
  const int tid = threadIdx.x;
  const int wave = tid >> 6, lane = tid & 63;
  const int qh = wave >> 1, par = wave & 1;
  const int g = lane >> 4, lc = lane & 15;
  const float qscale = 1.4426950408889634f / SF[0];  // exp2 domain

  const size_t base = (size_t)bh * Sn * Dn;
  const char* Kg = (const char*)(Kb + base);   // + kt*8192
  const char* Vg = (const char*)(Vt + base);   // + kt*128 (row stride 4096B)
  const int nkv = qt + 1;
  const int npairs = (nkv + 1) >> 1;

  int qg[2];
  qg[0] = qt * 64 + qh * 32 + lc;
  qg[1] = qg[0] + 16;

  // hoisted fragment LDS offsets (identical maps to R11)
  int ka[4][2], va[2][4];
#pragma unroll
  for (int t = 0; t < 4; ++t) {
    ka[t][0] = swz(t * 16 + lc, g * 16);
    ka[t][1] = swz(t * 16 + lc, g * 16 + 64);
  }
#pragma unroll
  for (int t2 = 0; t2 < 2; ++t2)
#pragma unroll
    for (int dt = 0; dt < 4; ++dt)
      va[t2][dt] = swz(dt * 16 + lc, t2 * 64 + g * 16);
  // staging source offsets (chunk = wave*2+j of 1KB within an 8KB tile)
  int koff[2], voff[2];
#pragma unroll
  for (int j = 0; j < 2; ++j) {
    int off = (wave * 2 + j) * 1024 + lane * 16;
    int row = off >> 7;
    int col = (off & 127) ^ ((row & 7) << 4);
    koff[j] = row * 128 + col;
    voff[j] = row * 4096 + col;
  }

  auto stageK = [&](int kt, int buf) {
    const char* src = Kg + (size_t)kt * 8192;
#pragma unroll
    for (int j = 0; j < 2; ++j)
      gl2lds16(src + koff[j], (char*)Kbuf[buf] + (wave * 2 + j) * 1024);
  };
  auto stageV = [&](int kt, int buf) {
    const char* src = Vg + (size_t)kt * 128;
#pragma unroll
    for (int j = 0; j < 2; ++j)
      gl2lds16(src + voff[j], (char*)Vbuf[buf] + (wave * 2 + j) * 1024);
  };

  // ---- Q fragments (B operand), both u, pre-scaled ----
  bf16x8 bq[2][2];
#pragma unroll
  for (int u = 0; u < 2; ++u) {
    const float* qp = Q + base + (size_t)qg[u] * Dn + g * 8;
#pragma unroll
    for (int h = 0; h < 2; ++h) {
      float4 x0 = *(const float4*)(qp + 32 * h);
      float4 x1 = *(const float4*)(qp + 32 * h + 4);
      bf16x8 a;
      a[0] = f2bf(x0.x * qscale); a[1] = f2bf(x0.y * qscale);
      a[2] = f2bf(x0.z * qscale); a[3] = f2bf(x0.w * qscale);
      a[4] = f2bf(x1.x * qscale); a[5] = f2bf(x1.y * qscale);
      a[6] = f2bf(x1.z * qscale); a[7] = f2bf(x1.w * qscale);
      bq[u][h] = a;
    }
  }

  bf16x8 ones;
#pragma unroll
  for (int j = 0; j < 8; ++j) ones[j] = (short)0x3F80;

  f32x4 o[2][4], lsum[2];
  float m[2] = {-10000.0f, -10000.0f};
#pragma unroll
  for (int u = 0; u < 2; ++u) {
    lsum[u] = (f32x4){0.f, 0.f, 0.f, 0.f};
#pragma unroll
    for (int dt = 0; dt < 4; ++dt) o[u][dt] = (f32x4){0.f, 0.f, 0.f, 0.f};
  }

  // prologue: stage pair 0
  stageK(0, 0);
  stageV(0, 0);
  if (nkv > 1) { stageK(1, 1); stageV(1, 1); }
  __syncthreads();

  for (int j = 0; j < npairs; ++j) {
    const int myt = 2 * j + par;
    if (myt < nkv) {
      const char* Kc = (const char*)Kbuf[par];
      const char* Vc = (const char*)Vbuf[par];

      // ---- QK^T: K-frags read once, used for both u ----
      f32x4 s[2][4];
      __builtin_amdgcn_s_setprio(1);
#pragma unroll
      for (int t = 0; t < 4; ++t) {
        bf16x8 ak0 = *(const bf16x8*)(Kc + ka[t][0]);
        bf16x8 ak1 = *(const bf16x8*)(Kc + ka[t][1]);
#pragma unroll
        for (int u = 0; u < 2; ++u) {
          f32x4 z = (f32x4){0.f, 0.f, 0.f, 0.f};
          z = MFMA32K(ak0, bq[u][0], z);
          z = MFMA32K(ak1, bq[u][1], z);
          s[u][t] = z;
        }
      }
      __builtin_amdgcn_s_setprio(0);

      if (myt == qt) {  // diagonal tile: causal mask
        const int kb = myt * KBLK;
#pragma unroll
        for (int u = 0; u < 2; ++u)
#pragma unroll
          for (int t = 0; t < 4; ++t)
#pragma unroll
            for (int i = 0; i < 4; ++i) {
              int kg = kb + t * 16 + g * 4 + i;
              if (kg > qg[u]) s[u][t][i] = -30000.0f;
            }
      }

      // ---- softmax per u (exp2 domain), defer-max THR=8, local gate ----
      union { unsigned uu[4]; bf16x8 v; } pb[2][2];
#pragma unroll
      for (int u = 0; u < 2; ++u) {
        float a0 = fmaxf(fmaxf(s[u][0][0], s[u][0][1]), s[u][0][2]);
        float a1 = fmaxf(fmaxf(s[u][0][3], s[u][1][0]), s[u][1][1]);
        float a2 = fmaxf(fmaxf(s[u][1][2], s[u][1][3]), s[u][2][0]);
        float a3 = fmaxf(fmaxf(s[u][2][1], s[u][2][2]), s[u][2][3]);
        float a4 = fmaxf(fmaxf(s[u][3][0], s[u][3][1]), s[u][3][2]);
        float b0 = fmaxf(fmaxf(a0, a1), a2);
        float b1 = fmaxf(fmaxf(a3, a4), s[u][3][3]);
        float plocal = fmaxf(b0, b1);
        if (!__all(plocal - m[u] <= 8.0f)) {
          float pmax = xred_max(plocal);
          float mnew = fmaxf(m[u], pmax);
          float alpha = EXP2(m[u] - mnew);
          lsum[u][0] *= alpha;
#pragma unroll
          for (int dt = 0; dt < 4; ++dt) o[u][dt] *= alpha;
          m[u] = mnew;
        }
#pragma unroll
        for (int t = 0; t < 4; ++t)
#pragma unroll
          for (int i = 0; i < 4; ++i) s[u][t][i] = EXP2(s[u][t][i] - m[u]);
#pragma unroll
        for (int t2 = 0; t2 < 2; ++t2) {
          pb[u][t2].uu[0] = pk_bf16(s[u][2 * t2][0], s[u][2 * t2][1]);
          pb[u][t2].uu[1] = pk_bf16(s[u][2 * t2][2], s[u][2 * t2][3]);
          pb[u][t2].uu[2] = pk_bf16(s[u][2 * t2 + 1][0], s[u][2 * t2 + 1][1]);
          pb[u][t2].uu[3] = pk_bf16(s[u][2 * t2 + 1][2], s[u][2 * t2 + 1][3]);
        }
      }

      // ---- PV: V-frags read once, used for both u; + l via ones-MFMA ----
      __builtin_amdgcn_s_setprio(1);
#pragma unroll
      for (int t2 = 0; t2 < 2; ++t2) {
        lsum[0] = MFMA32K(ones, pb[0][t2].v, lsum[0]);
        lsum[1] = MFMA32K(ones, pb[1][t2].v, lsum[1]);
#pragma unroll
        for (int dt = 0; dt < 4; ++dt) {
          bf16x8 av = *(const bf16x8*)(Vc + va[t2][dt]);
          o[0][dt] = MFMA32K(av, pb[0][t2].v, o[0][dt]);
          o[1][dt] = MFMA32K(av, pb[1][t2].v, o[1][dt]);
        }
      }
      __builtin_amdgcn_s_setprio(0);
    }

    __syncthreads();  // all reads of this pair done

    const int nt0 = 2 * j + 2;
    if (nt0 < nkv) { stageK(nt0, 0); stageV(nt0, 0); }
    if (nt0 + 1 < nkv) { stageK(nt0 + 1, 1); stageV(nt0 + 1, 1); }
    __syncthreads();  // next pair resident (per-wave vmcnt drained at barrier)
  }

  // ---- merge parity partials (per q-half) via LDS, then write O ----
  float* scr = (qh == 0) ? (float*)&Kbuf[0][0] : (float*)&Vbuf[0][0];
  if (par == 1) {
#pragma unroll
    for (int u = 0; u < 2; ++u) {
#pragma unroll
      for (int dt = 0; dt < 4; ++dt)
        *(f32x4*)(scr + (u * 16 + lc) * 64 + dt * 16 + g * 4) = o[u][dt];
      if (g == 0) {
        scr[2048 + u * 16 + lc] = m[u];
        scr[2080 + u * 16 + lc] = lsum[u][0];
      }
    }
  }
  __syncthreads();
  if (par == 0) {
#pragma unroll
    for (int u = 0; u < 2; ++u) {
      float mB = scr[2048 + u * 16 + lc];
      float lB = scr[2080 + u * 16 + lc];
      float M = fmaxf(m[u], mB);
      float aA = EXP2(m[u] - M), aB = EXP2(mB - M);
      float inv = 1.0f / (lsum[u][0] * aA + lB * aB);
      float cA = aA * inv, cB = aB * inv;
      float* op = O + base + (size_t)qg[u] * Dn;
#pragma unroll
      for (int dt = 0; dt < 4; ++dt) {
        f32x4 oB = *(const f32x4*)(scr + (u * 16 + lc) * 64 + dt * 16 + g * 4);
        f32x4 r = o[u][dt] * cA + oB * cB;
        *(f32x4*)(op + dt * 16 + g * 4) = r;
      }
    }
  }
}

extern "C" void kernel_launch(void* const* d_in, const int* in_sizes, int n_in,
                              void* d_out, int out_size, void* d_ws, size_t ws_size,
                              hipStream_t stream) {
  const float* Q = (const float*)d_in[0];
  const float* K = (const float*)d_in[1];
  const float* V = (const float*)d_in[2];
  const float* SF = (const float*)d_in[3];
  // d_in[4] causal mask: tril by construction -> applied analytically (k<=q).
  float* O = (float*)d_out;

  short* Kb = (short*)d_ws;  // [B*H][2048][64] bf16
  short* Vt = Kb + NE;       // [B*H][64][2048] bf16 (column-permuted per tile)

  prep<<<dim3(Sn / 64, Bsz * Hn), 256, 0, stream>>>(K, V, Kb, Vt);
  attn_fwd<<<dim3(Bsz * Hn, Sn / 64), 256, 0, stream>>>(Q, Kb, Vt, SF, O);
}

// Round 18
// 44.359 us; speedup vs baseline: 1.9966x; 1.0008x over previous
//
#include <hip/hip_runtime.h>
#include <hip/hip_bf16.h>

// Causal attention, B=2 H=16 S=2048 D=64, fp32 in/out.
// R18 = R15 verbatim (best verified: 44.4us total). The k-half/single-
// barrier line (R16/R17) failed correctness twice with algebra verified --
// abandoned. This re-banks the proven kernel:
// q-half x KV-parity wave split; K/V LDS fragments read once per tile,
// reused for both q-fragments; private (m,l,o) per wave merged once per
// block via LDS; swapped QK^T; in-register softmax (native exp2, defer-max
// local gate); MFMA l-sum (ones); permuted-V^T zero-conflict b128 PV;
// permlane reduce; setprio; pair-wise global_load_lds staging; heavy-first.

typedef __attribute__((ext_vector_type(8))) short bf16x8;
typedef __attribute__((ext_vector_type(4))) float f32x4;
typedef unsigned uint2v __attribute__((ext_vector_type(2)));

#define MFMA32K(a, b, c) __builtin_amdgcn_mfma_f32_16x16x32_bf16(a, b, c, 0, 0, 0)

constexpr int Bsz = 2, Hn = 16, Sn = 2048, Dn = 64;
constexpr int KBLK = 64;
constexpr int NE = Bsz * Hn * Sn * Dn;

#if defined(__has_builtin)
#if __has_builtin(__builtin_amdgcn_exp2f)
#define EXP2(x) __builtin_amdgcn_exp2f(x)
#endif
#endif
#ifndef EXP2
#define EXP2(x) exp2f(x)
#endif

__device__ inline short f2bf(float f) {
  union { float f; unsigned u; } v;
  v.f = f;
  unsigned r = v.u + 0x7FFF + ((v.u >> 16) & 1);  // RNE
  return (short)(r >> 16);
}

__device__ inline unsigned pk_bf16(float lo, float hi) {
  unsigned r;
  asm("v_cvt_pk_bf16_f32 %0, %1, %2" : "=v"(r) : "v"(lo), "v"(hi));
  return r;
}

__device__ inline void gl2lds16(const void* g, void* l) {
  __builtin_amdgcn_global_load_lds(
      (const __attribute__((address_space(1))) unsigned int*)g,
      (__attribute__((address_space(3))) unsigned int*)l, 16, 0, 0);
}

// tile rows = 128B; XOR 16B-slot index with row&7 (involution, both sides)
__device__ inline int swz(int row, int colbyte) {
  return row * 128 + (colbyte ^ ((row & 7) << 4));
}

#if defined(__has_builtin)
#if __has_builtin(__builtin_amdgcn_permlane16_swap) && \
    __has_builtin(__builtin_amdgcn_permlane32_swap)
#define HAVE_PERMLANE_SWAP 1
#endif
#endif

__device__ inline float xred_max(float x) {
#ifdef HAVE_PERMLANE_SWAP
  uint2v a = __builtin_amdgcn_permlane16_swap(__float_as_uint(x),
                                              __float_as_uint(x), false, false);
  x = fmaxf(__uint_as_float(a[0]), __uint_as_float(a[1]));
  uint2v b = __builtin_amdgcn_permlane32_swap(__float_as_uint(x),
                                              __float_as_uint(x), false, false);
  x = fmaxf(__uint_as_float(b[0]), __uint_as_float(b[1]));
#else
  x = fmaxf(x, __shfl_xor(x, 16, 64));
  x = fmaxf(x, __shfl_xor(x, 32, 64));
#endif
  return x;
}

// ---------- fused prepass: K fp32->bf16 AND V -> V^T bf16 per tile ----------
// V^T columns permuted within each 64-tile (R11 16x16 map): position p holds
// k(p) = 32*(p>>5) + 16*((p>>2)&1) + 4*((p>>3)&3) + (p&3).
__global__ __launch_bounds__(256) void prep(const float* __restrict__ K,
                                            const float* __restrict__ V,
                                            short* __restrict__ Kb,
                                            short* __restrict__ Vt) {
  __shared__ short t[64][66];  // +2 pad
  const int tile = blockIdx.x, bh = blockIdx.y;
  const int tid = threadIdx.x;
  const int r = tid >> 2, c = (tid & 3) * 16;
  const size_t base = (size_t)bh * Sn * Dn;

  {
    const float* kp = K + base + (size_t)(tile * 64 + r) * Dn + c;
    float4 x0 = *(const float4*)(kp + 0);
    float4 x1 = *(const float4*)(kp + 4);
    float4 x2 = *(const float4*)(kp + 8);
    float4 x3 = *(const float4*)(kp + 12);
    bf16x8 w0, w1;
    w0[0] = f2bf(x0.x); w0[1] = f2bf(x0.y); w0[2] = f2bf(x0.z); w0[3] = f2bf(x0.w);
    w0[4] = f2bf(x1.x); w0[5] = f2bf(x1.y); w0[6] = f2bf(x1.z); w0[7] = f2bf(x1.w);
    w1[0] = f2bf(x2.x); w1[1] = f2bf(x2.y); w1[2] = f2bf(x2.z); w1[3] = f2bf(x2.w);
    w1[4] = f2bf(x3.x); w1[5] = f2bf(x3.y); w1[6] = f2bf(x3.z); w1[7] = f2bf(x3.w);
    short* op = Kb + base + (size_t)(tile * 64 + r) * Dn + c;
    *(bf16x8*)op = w0;
    *(bf16x8*)(op + 8) = w1;
  }
  {
    const float* vp = V + base + (size_t)(tile * 64 + r) * Dn + c;
    float4 x0 = *(const float4*)(vp + 0);
    float4 x1 = *(const float4*)(vp + 4);
    float4 x2 = *(const float4*)(vp + 8);
    float4 x3 = *(const float4*)(vp + 12);
    short* tr = &t[r][c];
    tr[0] = f2bf(x0.x); tr[1] = f2bf(x0.y); tr[2] = f2bf(x0.z); tr[3] = f2bf(x0.w);
    tr[4] = f2bf(x1.x); tr[5] = f2bf(x1.y); tr[6] = f2bf(x1.z); tr[7] = f2bf(x1.w);
    tr[8] = f2bf(x2.x); tr[9] = f2bf(x2.y); tr[10] = f2bf(x2.z); tr[11] = f2bf(x2.w);
    tr[12] = f2bf(x3.x); tr[13] = f2bf(x3.y); tr[14] = f2bf(x3.z); tr[15] = f2bf(x3.w);
    __syncthreads();
    short* op = Vt + base + (size_t)r * Sn + tile * 64 + c;
    bf16x8 w0, w1;
#pragma unroll
    for (int j = 0; j < 8; ++j) {
      int p0 = c + j, p1 = c + 8 + j;
      int k0 = 32 * (p0 >> 5) + 16 * ((p0 >> 2) & 1) + 4 * ((p0 >> 3) & 3) + (p0 & 3);
      int k1 = 32 * (p1 >> 5) + 16 * ((p1 >> 2) & 1) + 4 * ((p1 >> 3) & 3) + (p1 & 3);
      w0[j] = t[k0][r];
      w1[j] = t[k1][r];
    }
    *(bf16x8*)op = w0;
    *(bf16x8*)(op + 8) = w1;
  }
}

// ---------------------------- main attention ----------------------------
// 4 waves = (qh, par): wave = 2*qh + par. Wave owns q rows
// qt*64 + qh*32 + u*16 + lc (u=0,1) over KV tiles with kt&1 == par.
__global__ __launch_bounds__(256, 4) void attn_fwd(
    const float* __restrict__ Q, const short* __restrict__ Kb,
    const short* __restrict__ Vt, const float* __restrict__ SF,
    float* __restrict__ O) {
  __shared__ short Kbuf[2][64 * 64];   // buffer index = tile parity
  __shared__ short Vbuf[2][64 * 64];

  const int bh = blockIdx.x;
  const int qt = (gridDim.y - 1) - blockIdx.y;  // heavy-first, [0,32)
  const int tid = threadIdx.x;
  const int wave = tid >> 6, lane = tid & 63;
  const int qh = wave >> 1, par = wave & 1;
  const int g = lane >> 4, lc = lane & 15;
  const float qscale = 1.4426950408889634f / SF[0];  // exp2 domain

  const size_t base = (size_t)bh * Sn * Dn;
  const char* Kg = (const char*)(Kb + base);   // + kt*8192
  const char* Vg = (const char*)(Vt + base);   // + kt*128 (row stride 4096B)
  const int nkv = qt + 1;
  const int npairs = (nkv + 1) >> 1;

  int qg[2];
  qg[0] = qt * 64 + qh * 32 + lc;
  qg[1] = qg[0] + 16;

  // hoisted fragment LDS offsets (identical maps to R11)
  int ka[4][2], va[2][4];
#pragma unroll
  for (int t = 0; t < 4; ++t) {
    ka[t][0] = swz(t * 16 + lc, g * 16);
    ka[t][1] = swz(t * 16 + lc, g * 16 + 64);
  }
#pragma unroll
  for (int t2 = 0; t2 < 2; ++t2)
#pragma unroll
    for (int dt = 0; dt < 4; ++dt)
      va[t2][dt] = swz(dt * 16 + lc, t2 * 64 + g * 16);
  // staging source offsets (chunk = wave*2+j of 1KB within an 8KB tile)
  int koff[2], voff[2];
#pragma unroll
  for (int j = 0; j < 2; ++j) {
    int off = (wave * 2 + j) * 1024 + lane * 16;
    int row = off >> 7;
    int col = (off & 127) ^ ((row & 7) << 4);
    koff[j] = row * 128 + col;
    voff[j] = row * 4096 + col;
  }

  auto stageK = [&](int kt, int buf) {
    const char* src = Kg + (size_t)kt * 8192;
#pragma unroll
    for (int j = 0; j < 2; ++j)
      gl2lds16(src + koff[j], (char*)Kbuf[buf] + (wave * 2 + j) * 1024);
  };
  auto stageV = [&](int kt, int buf) {
    const char* src = Vg + (size_t)kt * 128;
#pragma unroll
    for (int j = 0; j < 2; ++j)
      gl2lds16(src + voff[j], (char*)Vbuf[buf] + (wave * 2 + j) * 1024);
  };

  // ---- Q fragments (B operand), both u, pre-scaled ----
  bf16x8 bq[2][2];
#pragma unroll
  for (int u = 0; u < 2; ++u) {
    const float* qp = Q + base + (size_t)qg[u] * Dn + g * 8;
#pragma unroll
    for (int h = 0; h < 2; ++h) {
      float4 x0 = *(const float4*)(qp + 32 * h);
      float4 x1 = *(const float4*)(qp + 32 * h + 4);
      bf16x8 a;
      a[0] = f2bf(x0.x * qscale); a[1] = f2bf(x0.y * qscale);
      a[2] = f2bf(x0.z * qscale); a[3] = f2bf(x0.w * qscale);
      a[4] = f2bf(x1.x * qscale); a[5] = f2bf(x1.y * qscale);
      a[6] = f2bf(x1.z * qscale); a[7] = f2bf(x1.w * qscale);
      bq[u][h] = a;
    }
  }

  bf16x8 ones;
#pragma unroll
  for (int j = 0; j < 8; ++j) ones[j] = (short)0x3F80;

  f32x4 o[2][4], lsum[2];
  float m[2] = {-10000.0f, -10000.0f};
#pragma unroll
  for (int u = 0; u < 2; ++u) {
    lsum[u] = (f32x4){0.f, 0.f, 0.f, 0.f};
#pragma unroll
    for (int dt = 0; dt < 4; ++dt) o[u][dt] = (f32x4){0.f, 0.f, 0.f, 0.f};
  }

  // prologue: stage pair 0
  stageK(0, 0);
  stageV(0, 0);
  if (nkv > 1) { stageK(1, 1); stageV(1, 1); }
  __syncthreads();

  for (int j = 0; j < npairs; ++j) {
    const int myt = 2 * j + par;
    if (myt < nkv) {
      const char* Kc = (const char*)Kbuf[par];
      const char* Vc = (const char*)Vbuf[par];

      // ---- QK^T: K-frags read once, used for both u ----
      f32x4 s[2][4];
      __builtin_amdgcn_s_setprio(1);
#pragma unroll
      for (int t = 0; t < 4; ++t) {
        bf16x8 ak0 = *(const bf16x8*)(Kc + ka[t][0]);
        bf16x8 ak1 = *(const bf16x8*)(Kc + ka[t][1]);
#pragma unroll
        for (int u = 0; u < 2; ++u) {
          f32x4 z = (f32x4){0.f, 0.f, 0.f, 0.f};
          z = MFMA32K(ak0, bq[u][0], z);
          z = MFMA32K(ak1, bq[u][1], z);
          s[u][t] = z;
        }
      }
      __builtin_amdgcn_s_setprio(0);

      if (myt == qt) {  // diagonal tile: causal mask
        const int kb = myt * KBLK;
#pragma unroll
        for (int u = 0; u < 2; ++u)
#pragma unroll
          for (int t = 0; t < 4; ++t)
#pragma unroll
            for (int i = 0; i < 4; ++i) {
              int kg = kb + t * 16 + g * 4 + i;
              if (kg > qg[u]) s[u][t][i] = -30000.0f;
            }
      }

      // ---- softmax per u (exp2 domain), defer-max THR=8, local gate ----
      union { unsigned uu[4]; bf16x8 v; } pb[2][2];
#pragma unroll
      for (int u = 0; u < 2; ++u) {
        float a0 = fmaxf(fmaxf(s[u][0][0], s[u][0][1]), s[u][0][2]);
        float a1 = fmaxf(fmaxf(s[u][0][3], s[u][1][0]), s[u][1][1]);
        float a2 = fmaxf(fmaxf(s[u][1][2], s[u][1][3]), s[u][2][0]);
        float a3 = fmaxf(fmaxf(s[u][2][1], s[u][2][2]), s[u][2][3]);
        float a4 = fmaxf(fmaxf(s[u][3][0], s[u][3][1]), s[u][3][2]);
        float b0 = fmaxf(fmaxf(a0, a1), a2);
        float b1 = fmaxf(fmaxf(a3, a4), s[u][3][3]);
        float plocal = fmaxf(b0, b1);
        if (!__all(plocal - m[u] <= 8.0f)) {
          float pmax = xred_max(plocal);
          float mnew = fmaxf(m[u], pmax);
          float alpha = EXP2(m[u] - mnew);
          lsum[u][0] *= alpha;
#pragma unroll
          for (int dt = 0; dt < 4; ++dt) o[u][dt] *= alpha;
          m[u] = mnew;
        }
#pragma unroll
        for (int t = 0; t < 4; ++t)
#pragma unroll
          for (int i = 0; i < 4; ++i) s[u][t][i] = EXP2(s[u][t][i] - m[u]);
#pragma unroll
        for (int t2 = 0; t2 < 2; ++t2) {
          pb[u][t2].uu[0] = pk_bf16(s[u][2 * t2][0], s[u][2 * t2][1]);
          pb[u][t2].uu[1] = pk_bf16(s[u][2 * t2][2], s[u][2 * t2][3]);
          pb[u][t2].uu[2] = pk_bf16(s[u][2 * t2 + 1][0], s[u][2 * t2 + 1][1]);
          pb[u][t2].uu[3] = pk_bf16(s[u][2 * t2 + 1][2], s[u][2 * t2 + 1][3]);
        }
      }

      // ---- PV: V-frags read once, used for both u; + l via ones-MFMA ----
      __builtin_amdgcn_s_setprio(1);
#pragma unroll
      for (int t2 = 0; t2 < 2; ++t2) {
        lsum[0] = MFMA32K(ones, pb[0][t2].v, lsum[0]);
        lsum[1] = MFMA32K(ones, pb[1][t2].v, lsum[1]);
#pragma unroll
        for (int dt = 0; dt < 4; ++dt) {
          bf16x8 av = *(const bf16x8*)(Vc + va[t2][dt]);
          o[0][dt] = MFMA32K(av, pb[0][t2].v, o[0][dt]);
          o[1][dt] = MFMA32K(av, pb[1][t2].v, o[1][dt]);
        }
      }
      __builtin_amdgcn_s_setprio(0);
    }

    __syncthreads();  // all reads of this pair done

    const int nt0 = 2 * j + 2;
    if (nt0 < nkv) { stageK(nt0, 0); stageV(nt0, 0); }
    if (nt0 + 1 < nkv) { stageK(nt0 + 1, 1); stageV(nt0 + 1, 1); }
    __syncthreads();  // next pair resident (per-wave vmcnt drained at barrier)
  }

  // ---- merge parity partials (per q-half) via LDS, then write O ----
  float* scr = (qh == 0) ? (float*)&Kbuf[0][0] : (float*)&Vbuf[0][0];
  if (par == 1) {
#pragma unroll
    for (int u = 0; u < 2; ++u) {
#pragma unroll
      for (int dt = 0; dt < 4; ++dt)
        *(f32x4*)(scr + (u * 16 + lc) * 64 + dt * 16 + g * 4) = o[u][dt];
      if (g == 0) {
        scr[2048 + u * 16 + lc] = m[u];
        scr[2080 + u * 16 + lc] = lsum[u][0];
      }
    }
  }
  __syncthreads();
  if (par == 0) {
#pragma unroll
    for (int u = 0; u < 2; ++u) {
      float mB = scr[2048 + u * 16 + lc];
      float lB = scr[2080 + u * 16 + lc];
      float M = fmaxf(m[u], mB);
      float aA = EXP2(m[u] - M), aB = EXP2(mB - M);
      float inv = 1.0f / (lsum[u][0] * aA + lB * aB);
      float cA = aA * inv, cB = aB * inv;
      float* op = O + base + (size_t)qg[u] * Dn;
#pragma unroll
      for (int dt = 0; dt < 4; ++dt) {
        f32x4 oB = *(const f32x4*)(scr + (u * 16 + lc) * 64 + dt * 16 + g * 4);
        f32x4 r = o[u][dt] * cA + oB * cB;
        *(f32x4*)(op + dt * 16 + g * 4) = r;
      }
    }
  }
}

extern "C" void kernel_launch(void* const* d_in, const int* in_sizes, int n_in,
                              void* d_out, int out_size, void* d_ws, size_t ws_size,
                              hipStream_t stream) {
  const float* Q = (const float*)d_in[0];
  const float* K = (const float*)d_in[1];
  const float* V = (const float*)d_in[2];
  const float* SF = (const float*)d_in[3];
  // d_in[4] causal mask: tril by construction -> applied analytically (k<=q).
  float* O = (float*)d_out;

  short* Kb = (short*)d_ws;  // [B*H][2048][64] bf16
  short* Vt = Kb + NE;       // [B*H][64][2048] bf16 (column-permuted per tile)

  prep<<<dim3(Sn / 64, Bsz * Hn), 256, 0, stream>>>(K, V, Kb, Vt);
  attn_fwd<<<dim3(Bsz * Hn, Sn / 64), 256, 0, stream>>>(Q, Kb, Vt, SF, O);
}